// Round 8
// baseline (909.068 us; speedup 1.0000x reference)
//
#include <hip/hip_runtime.h>
#include <cstddef>

// ---------------------------------------------------------------------------
// PolyaAKT interaction embedder, MI355X/gfx950.  Inputs fp32, output fp32.
// Control path (logits/GRU) high-precision for argmax fidelity; value path
// (experts/LN/proj) in bf16 MFMA.  Per-q dedup throughout.
// R13 (on top of R12's gruE/prepqsk fusions):
//  - top1 fused into kernelF: 4 lanes/token compute the exact per-e fp64
//    logit chains; 2-step strict-> butterfly == sequential first-max.
//    Removes a dispatch + g_top1 array.
//  - smallk: 8 q per block (1250 blocks), weights staged in LDS once per
//    block (123KB) -> 8x less L2 weight traffic.  Same arithmetic per q.
//  - qsk: As transposed to [kk][row(+pad)] -> a-reads are one broadcast
//    ds_read_b128 instead of 4 column-strided b32.
// ---------------------------------------------------------------------------

#define NQ 10000
#define TT 32768   // B*S

typedef __attribute__((ext_vector_type(8))) short bf16x8;
typedef __attribute__((ext_vector_type(4))) float f32x4;

__device__ double g_qs  [NQ * 256];      // q_summary (relu'd), fp64
__device__ double g_xgr [2 * 192];       // r-part of xg (+b_ih), fp64
__device__ float  g_xg0f[192];           // start_token @ W_ih^T + b_ih (fp32)
__device__ float  g_xq2 [NQ * 384];      // r-folded xg: [q][r][192] fp32
__device__ double g_lq  [NQ * 4];        // qs @ wgate[0:256]
__device__ float  g_m   [TT * 64];       // GRU hidden per token (fp32)
__device__ unsigned short g_w1t  [4 * 256 * 256];  // bf16 [e][n][k]
__device__ unsigned short g_w2t  [4 * 256 * 256];
__device__ unsigned short g_projt[512 * 256];      // bf16 [n(cor|inc)][k]
__device__ unsigned short g_qf   [NQ * 4 * 256];   // LN'd expert out, bf16

__device__ __forceinline__ float bf2f(unsigned short x) {
  return __uint_as_float(((unsigned)x) << 16);
}
__device__ __forceinline__ unsigned short f2bf(float f) {
  unsigned u = __float_as_uint(f);
  u += 0x7FFFu + ((u >> 16) & 1u);   // RNE
  return (unsigned short)(u >> 16);
}
__device__ __forceinline__ f32x4 mfma16(bf16x8 a, bf16x8 b, f32x4 c) {
  return __builtin_amdgcn_mfma_f32_16x16x32_bf16(a, b, c, 0, 0, 0);
}
// packed fp32 fma: c = a*b + c on both lanes of the pair (bit-identical to
// two scalar v_fma_f32, just one instruction).
__device__ __forceinline__ void pkfma(float2& c, float2 a, float2 b) {
  asm("v_pk_fma_f32 %0, %1, %2, %0" : "+v"(c) : "v"(a), "v"(b));
}

// fast fp64 exp (slow path only): range-reduced degree-10 poly, rel err ~2e-13.
__device__ __forceinline__ double fexp(double x) {
  const double L2E  = 1.4426950408889634074;
  const double LN2H = 6.93147180369123816490e-01;
  const double LN2L = 1.90821492927058770002e-10;
  double n = rint(x * L2E);
  int ni = (int)n;
  double r = fma(-n, LN2H, x);
  r = fma(-n, LN2L, r);
  double p = 2.7557319223985888e-07;
  p = fma(p, r, 2.7557319223985893e-06);
  p = fma(p, r, 2.4801587301587302e-05);
  p = fma(p, r, 1.9841269841269841e-04);
  p = fma(p, r, 1.3888888888888889e-03);
  p = fma(p, r, 8.3333333333333332e-03);
  p = fma(p, r, 4.1666666666666664e-02);
  p = fma(p, r, 1.6666666666666666e-01);
  p = fma(p, r, 0.5);
  p = fma(p, r, 1.0);
  p = fma(p, r, 1.0);
  return ldexp(p, ni);
}

// tanh via odd Taylor, |p| <= 0.25: abs err ~5e-11.
__device__ __forceinline__ double tpoly(double p) {
  const double p2 = p * p;
  double t = -1382.0 / 155925.0;          // p^11
  t = fma(t, p2, 62.0 / 2835.0);          // p^9
  t = fma(t, p2, -17.0 / 315.0);          // p^7
  t = fma(t, p2, 2.0 / 15.0);             // p^5
  t = fma(t, p2, -1.0 / 3.0);             // p^3
  t = fma(t, p2, 1.0);
  return p * t;
}

// ---------------------------------------------------------------------------
// prepqsk: blocks 0..63 = prep (bf16 weight tables + fp64 folds);
// blocks 64..691 = qsk fp64 GEMM (As transposed [kk][row+pad] -> broadcast
// b128 a-reads; per-element FMA chain order unchanged).
// ---------------------------------------------------------------------------
__global__ void __launch_bounds__(256) prepqsk_kernel(
    const float* __restrict__ expert_w1, const float* __restrict__ expert_w2,
    const float* __restrict__ proj_cor_w, const float* __restrict__ proj_inc_w,
    const float* __restrict__ resp_table, const float* __restrict__ reducer_w,
    const float* __restrict__ reducer_b,  const float* __restrict__ start_token,
    const float* __restrict__ gru_w_ih,   const float* __restrict__ gru_b_ih,
    const float* __restrict__ emb, const float* __restrict__ adapter_w,
    const float* __restrict__ adapter_b)
{
  __shared__ double red2f[128];   // prep: [rr][j]
  __shared__ __align__(16) float As[32][66];   // [kk][row], padded
  __shared__ __align__(16) float Bs[32][65];
  const int tid = threadIdx.x;

  if (blockIdx.x < 64) {
    // ---- prep ----
    if (blockIdx.x == 0) {
      if (tid < 128) {
        const int rr = tid >> 6, j = tid & 63;
        double acc = (double)reducer_b[j];
        for (int k = 0; k < 256; ++k)
          acc += (double)resp_table[rr * 256 + k] *
                 (double)reducer_w[(256 + k) * 64 + j];
        red2f[tid] = acc;
      }
      __syncthreads();
      if (tid < 192) {
        const double bih = (double)gru_b_ih[tid];
        double a0 = bih, a1 = bih, a2 = bih;
        for (int j = 0; j < 64; ++j) {
          const double w = (double)gru_w_ih[tid * 64 + j];
          a0 += red2f[j] * w;
          a1 += red2f[64 + j] * w;
          a2 += (double)start_token[j] * w;
        }
        g_xgr[tid] = a0; g_xgr[192 + tid] = a1; g_xg0f[tid] = (float)a2;
      }
    }
    const int idx0 = blockIdx.x * 256 + tid;
    const int stride = 64 * 256;
    for (int i = idx0; i < 4 * 256 * 256; i += stride) {
      const int e = i >> 16, rem = i & 65535, n = rem >> 8, k = rem & 255;
      g_w1t[i] = f2bf(expert_w1[e * 65536 + k * 256 + n]);
      g_w2t[i] = f2bf(expert_w2[e * 65536 + k * 256 + n]);
    }
    for (int i = idx0; i < 512 * 256; i += stride) {
      const int n = i >> 8, k = i & 255;
      g_projt[i] = f2bf((n < 256) ? proj_cor_w[k * 256 + n]
                                  : proj_inc_w[k * 256 + (n - 256)]);
    }
    return;
  }

  // ---- qsk ----
  const int bq = blockIdx.x - 64;
  const int q0 = (bq >> 2) * 64;
  const int n0 = (bq & 3) * 64;
  const int ty = tid >> 4, tx = tid & 15;

  double acc[4][4];
#pragma unroll
  for (int i = 0; i < 4; ++i)
#pragma unroll
    for (int j = 0; j < 4; ++j) acc[i][j] = 0.0;

  const int arow = tid >> 2, aks = (tid & 3) * 8;
  const int qa = min(q0 + arow, NQ - 1);
  const int bkk = tid >> 3, bns = (tid & 7) * 8;

  for (int kc = 0; kc < 1024; kc += 32) {
    f32x4 av0 = *(const f32x4*)(emb + (size_t)qa * 1024 + kc + aks);
    f32x4 av1 = *(const f32x4*)(emb + (size_t)qa * 1024 + kc + aks + 4);
    f32x4 bv0 = *(const f32x4*)(adapter_w + (size_t)(kc + bkk) * 256 + n0 + bns);
    f32x4 bv1 = *(const f32x4*)(adapter_w + (size_t)(kc + bkk) * 256 + n0 + bns + 4);
    __syncthreads();
#pragma unroll
    for (int i = 0; i < 4; ++i) {
      As[aks + i][arow] = av0[i];
      As[aks + 4 + i][arow] = av1[i];
      Bs[bkk][bns + i] = bv0[i];
      Bs[bkk][bns + 4 + i] = bv1[i];
    }
    __syncthreads();
#pragma unroll 4
    for (int kk = 0; kk < 32; ++kk) {
      const f32x4 af = *(const f32x4*)&As[kk][ty * 4];   // broadcast b128
      const f32x4 bf = *(const f32x4*)&Bs[kk][tx * 4];
      double a[4], b[4];
#pragma unroll
      for (int i = 0; i < 4; ++i) a[i] = (double)af[i];
#pragma unroll
      for (int j = 0; j < 4; ++j) b[j] = (double)bf[j];
#pragma unroll
      for (int i = 0; i < 4; ++i)
#pragma unroll
        for (int j = 0; j < 4; ++j) acc[i][j] = fma(a[i], b[j], acc[i][j]);
    }
  }
#pragma unroll
  for (int i = 0; i < 4; ++i) {
    const int qrow = q0 + ty * 4 + i;
    if (qrow < NQ) {
#pragma unroll
      for (int j = 0; j < 4; ++j) {
        const int n = n0 + tx * 4 + j;
        double v = acc[i][j] + (double)adapter_b[n];
        g_qs[(size_t)qrow * 256 + n] = v > 0.0 ? v : 0.0;
      }
    }
  }
}

// ---------------------------------------------------------------------------
// smallk: 8 q per block (1250 blocks); reducer_w / gru_w_ih / wgate_w staged
// in LDS once per block (8x less L2 weight traffic).  Per-q arithmetic and
// ordering byte-identical to the 1-q version.
// ---------------------------------------------------------------------------
__global__ void __launch_bounds__(256) smallk_kernel(
    const float* __restrict__ reducer_w, const float* __restrict__ gru_w_ih,
    const float* __restrict__ wgate_w)
{
  __shared__ float rwl[256 * 64];    // 64KB
  __shared__ float gwl[192 * 64];    // 48KB
  __shared__ float wgl[256 * 4];     // 4KB
  __shared__ double qsr[256];
  __shared__ double ps[4][64];
  __shared__ double gi[64];
  const int tid = threadIdx.x;

  for (int i = tid; i < 256 * 64; i += 256) rwl[i] = reducer_w[i];
  for (int i = tid; i < 192 * 64; i += 256) gwl[i] = gru_w_ih[i];
  for (int i = tid; i < 256 * 4; i += 256) wgl[i] = wgate_w[i];

  for (int g = 0; g < 8; ++g) {
    const int qq = blockIdx.x * 8 + g;
    __syncthreads();
    qsr[tid] = g_qs[(size_t)qq * 256 + tid];
    __syncthreads();
    {
      const int j = tid & 63, h = tid >> 6;
      const int k0 = h * 64;
      double a0 = 0.0, a1 = 0.0, a2 = 0.0, a3 = 0.0;
      for (int k = 0; k < 64; k += 4) {
        a0 = fma(qsr[k0 + k + 0], (double)rwl[(k0 + k + 0) * 64 + j], a0);
        a1 = fma(qsr[k0 + k + 1], (double)rwl[(k0 + k + 1) * 64 + j], a1);
        a2 = fma(qsr[k0 + k + 2], (double)rwl[(k0 + k + 2) * 64 + j], a2);
        a3 = fma(qsr[k0 + k + 3], (double)rwl[(k0 + k + 3) * 64 + j], a3);
      }
      ps[h][j] = (a0 + a1) + (a2 + a3);
    }
    __syncthreads();
    if (tid < 64) gi[tid] = (ps[0][tid] + ps[1][tid]) + (ps[2][tid] + ps[3][tid]);
    if (tid >= 64 && tid < 68) {
      const int e = tid - 64;
      double a0 = 0.0, a1 = 0.0, a2 = 0.0, a3 = 0.0;
      for (int k = 0; k < 256; k += 4) {
        a0 = fma(qsr[k + 0], (double)wgl[(k + 0) * 4 + e], a0);
        a1 = fma(qsr[k + 1], (double)wgl[(k + 1) * 4 + e], a1);
        a2 = fma(qsr[k + 2], (double)wgl[(k + 2) * 4 + e], a2);
        a3 = fma(qsr[k + 3], (double)wgl[(k + 3) * 4 + e], a3);
      }
      g_lq[(size_t)qq * 4 + e] = (a0 + a1) + (a2 + a3);
    }
    __syncthreads();
    if (tid < 192) {
      double a0 = 0.0, a1 = 0.0, a2 = 0.0, a3 = 0.0;
      for (int k = 0; k < 64; k += 4) {
        a0 = fma(gi[k + 0], (double)gwl[tid * 64 + k + 0], a0);
        a1 = fma(gi[k + 1], (double)gwl[tid * 64 + k + 1], a1);
        a2 = fma(gi[k + 2], (double)gwl[tid * 64 + k + 2], a2);
        a3 = fma(gi[k + 3], (double)gwl[tid * 64 + k + 3], a3);
      }
      const double s = (a0 + a1) + (a2 + a3);
      // r-folded x values (fp32): one extra rounding ~1e-8, below the
      // reference's own fp32 noise -> argmax decisions unaffected.
      g_xq2[(size_t)qq * 384 + tid]       = (float)(s + g_xgr[tid]);
      g_xq2[(size_t)qq * 384 + 192 + tid] = (float)(s + g_xgr[192 + tid]);
    }
  }
}

// ---------------------------------------------------------------------------
// gruE: blocks 0..63 = gru (2-wave k-split, resident W, padded HF);
// blocks 64..1315 = kernelE (expert-split, flattened (313,4)).
// ---------------------------------------------------------------------------
__global__ void __attribute__((amdgpu_waves_per_eu(1, 1)))
__launch_bounds__(128, 1) gruE_kernel(
    const int* __restrict__ q, const int* __restrict__ r,
    const float* __restrict__ whh, const float* __restrict__ bhh,
    const float* __restrict__ emb,
    const float* __restrict__ b1, const float* __restrict__ b2,
    const float* __restrict__ lng, const float* __restrict__ lnb)
{
  __shared__ __align__(16) float HF[2][68];   // gru: h mirror, padded
  __shared__ __align__(16) unsigned short QR[32 * 264];
  __shared__ __align__(16) unsigned short H1[32 * 264];
  __shared__ __align__(16) unsigned short EO[32 * 264];
  const int tid = threadIdx.x;

  if (blockIdx.x < 64) {
    // ---- gru ----
    const int b = blockIdx.x;
    const int wv = tid >> 6;           // wave: rows [wv*32, wv*32+32)
    const int l = tid & 63;
    const int p = l >> 1;              // row within wave
    const int half = l & 1;            // k-half
    const int j = wv * 32 + p;         // row
    const int k0 = half * 32;

    // W half-rows for this lane, fp32 float2 pairs, resident (96 VGPRs).
    float2 Wr[16], Wz[16], Wn[16];
#pragma unroll
    for (int i = 0; i < 16; ++i) {
      Wr[i] = *(const float2*)(whh + (size_t)(0 * 64 + j) * 64 + k0 + 2 * i);
      Wz[i] = *(const float2*)(whh + (size_t)(1 * 64 + j) * 64 + k0 + 2 * i);
      Wn[i] = *(const float2*)(whh + (size_t)(2 * 64 + j) * 64 + k0 + 2 * i);
    }
#pragma unroll
    for (int i = 0; i < 16; ++i) {
      asm volatile("" : "+v"(Wr[i]));
      asm volatile("" : "+v"(Wz[i]));
      asm volatile("" : "+v"(Wn[i]));
    }
    const double br = (double)bhh[j];
    const double bz = (double)bhh[64 + j];
    const double bn = (double)bhh[128 + j];

    // step 0 consumes the start token (b_ih already folded in g_xg0f)
    float cx0 = g_xg0f[j], cx1 = g_xg0f[64 + j], cx2 = g_xg0f[128 + j];
    int qA = q[b * 512], rA = r[b * 512];

    const int jpad = j + ((j >> 5) << 2);     // +4 words for rows 32..63
    if (tid < 64) {
      const int tp = tid + ((tid >> 5) << 2);
      HF[0][tp] = 0.f;
    }
    double hd = 0.0;
    asm volatile("s_waitcnt lgkmcnt(0)\n\ts_barrier" ::: "memory");

    for (int t = 0; t < 512; ++t) {
      // prefetch x for step t+1 (token t) and q/r for token t+1
      float nx0 = 0.f, nx1 = 0.f, nx2 = 0.f;
      int qB = qA, rB = rA;
      if (t < 511) {
        const size_t base = (size_t)(qA * 2 + rA) * 192 + j;
        nx0 = g_xq2[base];
        nx1 = g_xq2[base + 64];
        nx2 = g_xq2[base + 128];
        const int tk = min(t + 1, 510);
        qB = q[b * 512 + tk];
        rB = r[b * 512 + tk];
      }

      // half-dot: 48 packed fp32 FMAs against resident W
      float2 ar = {0.f, 0.f}, az = {0.f, 0.f}, an = {0.f, 0.f};
      {
        const float4* hp = (const float4*)&HF[t & 1][half * 36];
#pragma unroll
        for (int g = 0; g < 8; ++g) {
          const float4 t4 = hp[g];
          const float2 hA = make_float2(t4.x, t4.y);
          const float2 hB = make_float2(t4.z, t4.w);
          pkfma(ar, Wr[2 * g], hA); pkfma(ar, Wr[2 * g + 1], hB);
          pkfma(az, Wz[2 * g], hA); pkfma(az, Wz[2 * g + 1], hB);
          pkfma(an, Wn[2 * g], hA); pkfma(an, Wn[2 * g + 1], hB);
        }
      }
      // combine k-halves in-pair (fp64 add is commutative -> pair-uniform)
      const float srh = ar.x + ar.y;
      const float szh = az.x + az.y;
      const float snh = an.x + an.y;
      const float sro = __shfl_xor(srh, 1);
      const float szo = __shfl_xor(szh, 1);
      const float sno = __shfl_xor(snh, 1);
      const double hr = br + ((double)srh + (double)sro);
      const double hz = bz + ((double)szh + (double)szo);
      const double hn = bn + ((double)snh + (double)sno);
      const double pr = (double)cx0 + hr, pz = (double)cx1 + hz;
      const double xn = (double)cx2;
      double rg = fma(0.5, tpoly(0.5 * pr), 0.5);
      double zg = fma(0.5, tpoly(0.5 * pz), 0.5);
      double pre = fma(rg, hn, xn);
      double ng = tpoly(pre);
      const bool bad = (fabs(pr) > 0.5) | (fabs(pz) > 0.5) | (fabs(pre) > 0.25);
      if (bad) {   // rare slow path
        rg = 1.0 / (1.0 + fexp(-pr));
        zg = 1.0 / (1.0 + fexp(-pz));
        pre = fma(rg, hn, xn);
        ng = 1.0 - 2.0 / (fexp(pre + pre) + 1.0);
      }
      const double hnew = fma(zg, hd - ng, ng);   // (1-z)n + z h
      hd = hnew;
      const float hnf = (float)hnew;
      if (half == 0) {
        HF[(t & 1) ^ 1][jpad] = hnf;
        g_m[((size_t)b * 512 + t) * 64 + j] = hnf;
      }
      asm volatile("s_waitcnt lgkmcnt(0)\n\ts_barrier" ::: "memory");

      cx0 = nx0; cx1 = nx1; cx2 = nx2;
      qA = qB; rA = rB;
    }
    return;
  }

  // ---- kernelE ----
  const int bx = blockIdx.x - 64;
  const int e  = bx & 3;
  const int t0 = (bx >> 2) * 32;
  const int w = tid >> 6;
  const int lane = tid & 63;
  const int l15 = lane & 15;
  const int quad = lane >> 4;

  // stage expert-e slice: 32 rows x 256 cols fp32 -> bf16
  for (int c = 0; c < 16; ++c) {
    const int idx = c * 128 + tid;           // f32x4 chunks: 32 rows x 64
    const int row = idx >> 6, col4 = idx & 63;
    const int qv = min(t0 + row, NQ - 1);
    f32x4 v = *(const f32x4*)(emb + (size_t)qv * 1024 + e * 256 + col4 * 4);
    unsigned a = ((unsigned)f2bf(v[1]) << 16) | f2bf(v[0]);
    unsigned bb = ((unsigned)f2bf(v[3]) << 16) | f2bf(v[2]);
    *(uint2*)&QR[row * 264 + col4 * 4] = make_uint2(a, bb);
  }
  __syncthreads();

  const f32x4 z4 = {0.f, 0.f, 0.f, 0.f};
  const int n0 = w * 128;

  f32x4 acc[2][8];
#pragma unroll
  for (int a = 0; a < 2; ++a)
#pragma unroll
    for (int bq = 0; bq < 8; ++bq) acc[a][bq] = z4;
#pragma unroll
  for (int ks = 0; ks < 8; ++ks) {
    const int koff = ks * 32 + quad * 8;
    bf16x8 a0 = *(const bf16x8*)&QR[l15 * 264 + koff];
    bf16x8 a1 = *(const bf16x8*)&QR[(16 + l15) * 264 + koff];
#pragma unroll
    for (int nt = 0; nt < 8; ++nt) {
      bf16x8 bbv = *(const bf16x8*)(g_w1t + (size_t)e * 65536 +
                                    (size_t)(n0 + nt * 16 + l15) * 256 + koff);
      acc[0][nt] = mfma16(a0, bbv, acc[0][nt]);
      acc[1][nt] = mfma16(a1, bbv, acc[1][nt]);
    }
  }
#pragma unroll
  for (int nt = 0; nt < 8; ++nt) {
    const int n = n0 + nt * 16 + l15;
    const float b1v = b1[e * 256 + n];
#pragma unroll
    for (int mt = 0; mt < 2; ++mt)
#pragma unroll
      for (int rg = 0; rg < 4; ++rg) {
        const int m = mt * 16 + quad * 4 + rg;
        H1[m * 264 + n] = f2bf(fmaxf(acc[mt][nt][rg] + b1v, 0.f));
      }
  }
  __syncthreads();

  f32x4 acc2[2][8];
#pragma unroll
  for (int a = 0; a < 2; ++a)
#pragma unroll
    for (int bq = 0; bq < 8; ++bq) acc2[a][bq] = z4;
#pragma unroll
  for (int ks = 0; ks < 8; ++ks) {
    const int koff = ks * 32 + quad * 8;
    bf16x8 a0 = *(const bf16x8*)&H1[l15 * 264 + koff];
    bf16x8 a1 = *(const bf16x8*)&H1[(16 + l15) * 264 + koff];
#pragma unroll
    for (int nt = 0; nt < 8; ++nt) {
      bf16x8 bbv = *(const bf16x8*)(g_w2t + (size_t)e * 65536 +
                                    (size_t)(n0 + nt * 16 + l15) * 256 + koff);
      acc2[0][nt] = mfma16(a0, bbv, acc2[0][nt]);
      acc2[1][nt] = mfma16(a1, bbv, acc2[1][nt]);
    }
  }
#pragma unroll
  for (int nt = 0; nt < 8; ++nt) {
    const int n = n0 + nt * 16 + l15;
    const float b2v = b2[e * 256 + n];
#pragma unroll
    for (int mt = 0; mt < 2; ++mt)
#pragma unroll
      for (int rg = 0; rg < 4; ++rg) {
        const int m = mt * 16 + quad * 4 + rg;
        EO[m * 264 + n] = f2bf(acc2[mt][nt][rg] + b2v);
      }
  }
  __syncthreads();

  {
    const int m = tid >> 2;
    const int sub = tid & 3;
    float sx = 0.f, sxx = 0.f;
#pragma unroll
    for (int i = 0; i < 8; ++i) {
      bf16x8 v = *(const bf16x8*)&EO[m * 264 + sub * 64 + i * 8];
#pragma unroll
      for (int c = 0; c < 8; ++c) {
        const float f = bf2f((unsigned short)v[c]);
        sx += f; sxx += f * f;
      }
    }
    sx += __shfl_xor(sx, 1); sxx += __shfl_xor(sxx, 1);
    sx += __shfl_xor(sx, 2); sxx += __shfl_xor(sxx, 2);
    const float mu = sx * (1.f / 256.f);
    const float var = sxx * (1.f / 256.f) - mu * mu;
    const float inv = 1.f / sqrtf(var + 1e-5f);
    if (t0 + m < NQ) {
      const size_t base = ((size_t)(t0 + m) * 4 + e) * 256;
#pragma unroll
      for (int i = 0; i < 8; ++i) {
        const int dbase = sub * 64 + i * 8;
        bf16x8 v = *(const bf16x8*)&EO[m * 264 + dbase];
        bf16x8 ov;
#pragma unroll
        for (int c = 0; c < 8; ++c) {
          const int d = dbase + c;
          const float f = bf2f((unsigned short)v[c]);
          ov[c] = (short)f2bf(lng[d] * (f - mu) * inv + lnb[d]);
        }
        *(bf16x8*)(g_qf + base + dbase) = ov;
      }
    }
  }
}

// ---------------------------------------------------------------------------
// kernelF: top1 fused.  Per 32 tokens: 4 lanes/token compute the exact
// per-e fp64 logit chains (same order as the old top1), 2-step strict->
// butterfly == sequential first-max; then gather qf[q_t][top1] -> q_fused
// out (fp32) and LDS; proj (cor|inc) bf16 MFMA; qa_fused by r.
// ---------------------------------------------------------------------------
__global__ void __launch_bounds__(128) kernelF(
    const int* __restrict__ q, const int* __restrict__ r,
    const float* __restrict__ wgate_w, const float* __restrict__ wgate_b,
    const float* __restrict__ pcb, const float* __restrict__ pib,
    float* __restrict__ out)
{
  __shared__ __align__(16) unsigned short QF[32 * 264];
  __shared__ double w2d[256];   // [j][e]
  __shared__ int rv_l[32];
  const int tid = threadIdx.x;
  const int t0 = blockIdx.x * 32;
  const int w = tid >> 6;
  const int lane = tid & 63;
  const int l15 = lane & 15;
  const int quad = lane >> 4;
  if (tid < 32) rv_l[tid] = r[t0 + tid];
  w2d[tid] = (double)wgate_w[1024 + tid];
  w2d[128 + tid] = (double)wgate_w[1152 + tid];
  __syncthreads();

  // ---- top1 (fused): token = tid>>2, e = tid&3 ----
  int bi;
  {
    const int tok = tid >> 2;
    const int e = tid & 3;
    const int t = t0 + tok;
    const int qv = q[t];
    double le = g_lq[(size_t)qv * 4 + e] + (double)wgate_b[e];
    const f32x4* mr4 = (const f32x4*)(g_m + (size_t)t * 64);
#pragma unroll 4
    for (int jj = 0; jj < 16; ++jj) {
      const f32x4 mv4 = mr4[jj];
#pragma unroll
      for (int c = 0; c < 4; ++c)
        le = fma((double)mv4[c], w2d[(jj * 4 + c) * 4 + e], le);
    }
    double v = le; bi = e;
    {   // pair {e,e^1}: winner = hi iff l_hi > l_lo (first-max)
      const double vo = __shfl_xor(v, 1);
      const int bo = __shfl_xor(bi, 1);
      const bool ilow = (e & 1) == 0;
      const double vl = ilow ? v : vo, vh = ilow ? vo : v;
      const int bl = ilow ? bi : bo, bh = ilow ? bo : bi;
      if (vh > vl) { v = vh; bi = bh; } else { v = vl; bi = bl; }
    }
    {   // pair {01,23}
      const double vo = __shfl_xor(v, 2);
      const int bo = __shfl_xor(bi, 2);
      const bool ilow = (e & 2) == 0;
      const double vl = ilow ? v : vo, vh = ilow ? vo : v;
      const int bl = ilow ? bi : bo, bh = ilow ? bo : bi;
      if (vh > vl) { v = vh; bi = bh; } else { v = vl; bi = bl; }
    }
  }

  {
    const int m = tid >> 2;
    const size_t row = ((size_t)q[t0 + m] * 4 + bi) * 256;
#pragma unroll
    for (int i = 0; i < 8; ++i) {
      const int dbase = (tid & 3) * 64 + i * 8;
      bf16x8 v = *(const bf16x8*)(g_qf + row + dbase);
      *(bf16x8*)&QF[m * 264 + dbase] = v;
      f32x4 f0, f1;
#pragma unroll
      for (int c = 0; c < 4; ++c) f0[c] = bf2f((unsigned short)v[c]);
#pragma unroll
      for (int c = 0; c < 4; ++c) f1[c] = bf2f((unsigned short)v[4 + c]);
      *(f32x4*)(out + (size_t)(t0 + m) * 256 + dbase) = f0;
      *(f32x4*)(out + (size_t)(t0 + m) * 256 + dbase + 4) = f1;
    }
  }
  __syncthreads();

  const f32x4 z4 = {0.f, 0.f, 0.f, 0.f};
  const int n0 = w * 128;
  for (int ph = 0; ph < 2; ++ph) {
    f32x4 acc[2][8];
#pragma unroll
    for (int a = 0; a < 2; ++a)
#pragma unroll
      for (int bq = 0; bq < 8; ++bq) acc[a][bq] = z4;
#pragma unroll
    for (int ks = 0; ks < 8; ++ks) {
      const int koff = ks * 32 + quad * 8;
      bf16x8 a0 = *(const bf16x8*)&QF[l15 * 264 + koff];
      bf16x8 a1 = *(const bf16x8*)&QF[(16 + l15) * 264 + koff];
#pragma unroll
      for (int nt = 0; nt < 8; ++nt) {
        bf16x8 bbv = *(const bf16x8*)(g_projt +
            (size_t)(ph * 256 + n0 + nt * 16 + l15) * 256 + koff);
        acc[0][nt] = mfma16(a0, bbv, acc[0][nt]);
        acc[1][nt] = mfma16(a1, bbv, acc[1][nt]);
      }
    }
    const float* pbb = ph ? pib : pcb;
    const int want = ph ? 0 : 1;
#pragma unroll
    for (int nt = 0; nt < 8; ++nt) {
      const int n = n0 + nt * 16 + l15;
      const float pbv = pbb[n];
#pragma unroll
      for (int mt = 0; mt < 2; ++mt)
#pragma unroll
        for (int rg = 0; rg < 4; ++rg) {
          const int m = mt * 16 + quad * 4 + rg;
          if (rv_l[m] == want)
            out[(size_t)TT * 256 + (size_t)(t0 + m) * 256 + n] =
                acc[mt][nt][rg] + pbv;
        }
    }
  }
}

// ---------------------------------------------------------------------------
extern "C" void kernel_launch(void* const* d_in, const int* in_sizes, int n_in,
                              void* d_out, int out_size, void* d_ws, size_t ws_size,
                              hipStream_t stream)
{
  const int*   q   = (const int*)d_in[0];
  const int*   r   = (const int*)d_in[1];
  const float* emb = (const float*)d_in[2];
  const float* ew1 = (const float*)d_in[3];
  const float* eb1 = (const float*)d_in[4];
  const float* ew2 = (const float*)d_in[5];
  const float* eb2 = (const float*)d_in[6];
  const float* aw  = (const float*)d_in[7];
  const float* ab  = (const float*)d_in[8];
  const float* rw  = (const float*)d_in[9];
  const float* rb  = (const float*)d_in[10];
  const float* st  = (const float*)d_in[11];
  const float* wih = (const float*)d_in[12];
  const float* whh = (const float*)d_in[13];
  const float* bih = (const float*)d_in[14];
  const float* bhh = (const float*)d_in[15];
  const float* wgw = (const float*)d_in[16];
  const float* wgb = (const float*)d_in[17];
  const float* lng = (const float*)d_in[18];
  const float* lnb = (const float*)d_in[19];
  const float* resp= (const float*)d_in[20];
  const float* pcw = (const float*)d_in[21];
  const float* pcb = (const float*)d_in[22];
  const float* piw = (const float*)d_in[23];
  const float* pib = (const float*)d_in[24];
  float* out = (float*)d_out;
  (void)bih; (void)in_sizes; (void)n_in; (void)d_ws; (void)ws_size; (void)out_size;

  prepqsk_kernel<<<692, 256, 0, stream>>>(ew1, ew2, pcw, piw, resp, rw, rb, st,
                                          wih, bih, emb, aw, ab);
  smallk_kernel<<<1250, 256, 0, stream>>>(rw, wih, wgw);
  gruE_kernel<<<64 + 313 * 4, 128, 0, stream>>>(q, r, whh, bhh,
                                                emb, eb1, eb2, lng, lnb);
  kernelF<<<1024, 128, 0, stream>>>(q, r, wgw, wgb, pcb, pib, out);
}

// Round 9
// 764.673 us; speedup vs baseline: 1.1888x; 1.1888x over previous
//
#include <hip/hip_runtime.h>
#include <cstddef>

// ---------------------------------------------------------------------------
// PolyaAKT interaction embedder, MI355X/gfx950.  Inputs fp32, output fp32.
// Control path (logits/GRU) high-precision for argmax fidelity; value path
// (experts/LN/proj) in bf16 MFMA.  Per-q dedup throughout.
// R14 = R12 + (top1 fused into kernelF) ONLY.
// R13 post-mortem: smallk's 118KB-LDS weight staging dropped it to 1
// block/CU with a serial 8-q loop (occupancy catastrophe; the L2 weight
// traffic it "saved" was a non-problem at 34.5 TB/s), and qsk's As
// transpose introduced 2-way write conflicts.  Both reverted to R12 form.
// Kept: kernelF computes top1 inline (4 lanes/token, exact fp64 chains,
// strict-> butterfly == sequential first-max) -- one fewer dispatch.
// ---------------------------------------------------------------------------

#define NQ 10000
#define TT 32768   // B*S

typedef __attribute__((ext_vector_type(8))) short bf16x8;
typedef __attribute__((ext_vector_type(4))) float f32x4;

__device__ double g_qs  [NQ * 256];      // q_summary (relu'd), fp64
__device__ double g_xgr [2 * 192];       // r-part of xg (+b_ih), fp64
__device__ float  g_xg0f[192];           // start_token @ W_ih^T + b_ih (fp32)
__device__ float  g_xq2 [NQ * 384];      // r-folded xg: [q][r][192] fp32
__device__ double g_lq  [NQ * 4];        // qs @ wgate[0:256]
__device__ float  g_m   [TT * 64];       // GRU hidden per token (fp32)
__device__ unsigned short g_w1t  [4 * 256 * 256];  // bf16 [e][n][k]
__device__ unsigned short g_w2t  [4 * 256 * 256];
__device__ unsigned short g_projt[512 * 256];      // bf16 [n(cor|inc)][k]
__device__ unsigned short g_qf   [NQ * 4 * 256];   // LN'd expert out, bf16

__device__ __forceinline__ float bf2f(unsigned short x) {
  return __uint_as_float(((unsigned)x) << 16);
}
__device__ __forceinline__ unsigned short f2bf(float f) {
  unsigned u = __float_as_uint(f);
  u += 0x7FFFu + ((u >> 16) & 1u);   // RNE
  return (unsigned short)(u >> 16);
}
__device__ __forceinline__ f32x4 mfma16(bf16x8 a, bf16x8 b, f32x4 c) {
  return __builtin_amdgcn_mfma_f32_16x16x32_bf16(a, b, c, 0, 0, 0);
}
// packed fp32 fma: c = a*b + c on both lanes of the pair (bit-identical to
// two scalar v_fma_f32, just one instruction).
__device__ __forceinline__ void pkfma(float2& c, float2 a, float2 b) {
  asm("v_pk_fma_f32 %0, %1, %2, %0" : "+v"(c) : "v"(a), "v"(b));
}

// fast fp64 exp (slow path only): range-reduced degree-10 poly, rel err ~2e-13.
__device__ __forceinline__ double fexp(double x) {
  const double L2E  = 1.4426950408889634074;
  const double LN2H = 6.93147180369123816490e-01;
  const double LN2L = 1.90821492927058770002e-10;
  double n = rint(x * L2E);
  int ni = (int)n;
  double r = fma(-n, LN2H, x);
  r = fma(-n, LN2L, r);
  double p = 2.7557319223985888e-07;
  p = fma(p, r, 2.7557319223985893e-06);
  p = fma(p, r, 2.4801587301587302e-05);
  p = fma(p, r, 1.9841269841269841e-04);
  p = fma(p, r, 1.3888888888888889e-03);
  p = fma(p, r, 8.3333333333333332e-03);
  p = fma(p, r, 4.1666666666666664e-02);
  p = fma(p, r, 1.6666666666666666e-01);
  p = fma(p, r, 0.5);
  p = fma(p, r, 1.0);
  p = fma(p, r, 1.0);
  return ldexp(p, ni);
}

// tanh via odd Taylor, |p| <= 0.25: abs err ~5e-11.
__device__ __forceinline__ double tpoly(double p) {
  const double p2 = p * p;
  double t = -1382.0 / 155925.0;          // p^11
  t = fma(t, p2, 62.0 / 2835.0);          // p^9
  t = fma(t, p2, -17.0 / 315.0);          // p^7
  t = fma(t, p2, 2.0 / 15.0);             // p^5
  t = fma(t, p2, -1.0 / 3.0);             // p^3
  t = fma(t, p2, 1.0);
  return p * t;
}

// ---------------------------------------------------------------------------
// prepqsk: blocks 0..63 = prep (bf16 weight tables + fp64 folds);
// blocks 64..691 = qsk fp64 GEMM (R12 layout).
// ---------------------------------------------------------------------------
__global__ void __launch_bounds__(256) prepqsk_kernel(
    const float* __restrict__ expert_w1, const float* __restrict__ expert_w2,
    const float* __restrict__ proj_cor_w, const float* __restrict__ proj_inc_w,
    const float* __restrict__ resp_table, const float* __restrict__ reducer_w,
    const float* __restrict__ reducer_b,  const float* __restrict__ start_token,
    const float* __restrict__ gru_w_ih,   const float* __restrict__ gru_b_ih,
    const float* __restrict__ emb, const float* __restrict__ adapter_w,
    const float* __restrict__ adapter_b)
{
  __shared__ double red2f[128];   // prep: [rr][j]
  __shared__ __align__(16) float As[64][33];
  __shared__ __align__(16) float Bs[32][65];
  const int tid = threadIdx.x;

  if (blockIdx.x < 64) {
    // ---- prep ----
    if (blockIdx.x == 0) {
      if (tid < 128) {
        const int rr = tid >> 6, j = tid & 63;
        double acc = (double)reducer_b[j];
        for (int k = 0; k < 256; ++k)
          acc += (double)resp_table[rr * 256 + k] *
                 (double)reducer_w[(256 + k) * 64 + j];
        red2f[tid] = acc;
      }
      __syncthreads();
      if (tid < 192) {
        const double bih = (double)gru_b_ih[tid];
        double a0 = bih, a1 = bih, a2 = bih;
        for (int j = 0; j < 64; ++j) {
          const double w = (double)gru_w_ih[tid * 64 + j];
          a0 += red2f[j] * w;
          a1 += red2f[64 + j] * w;
          a2 += (double)start_token[j] * w;
        }
        g_xgr[tid] = a0; g_xgr[192 + tid] = a1; g_xg0f[tid] = (float)a2;
      }
    }
    const int idx0 = blockIdx.x * 256 + tid;
    const int stride = 64 * 256;
    for (int i = idx0; i < 4 * 256 * 256; i += stride) {
      const int e = i >> 16, rem = i & 65535, n = rem >> 8, k = rem & 255;
      g_w1t[i] = f2bf(expert_w1[e * 65536 + k * 256 + n]);
      g_w2t[i] = f2bf(expert_w2[e * 65536 + k * 256 + n]);
    }
    for (int i = idx0; i < 512 * 256; i += stride) {
      const int n = i >> 8, k = i & 255;
      g_projt[i] = f2bf((n < 256) ? proj_cor_w[k * 256 + n]
                                  : proj_inc_w[k * 256 + (n - 256)]);
    }
    return;
  }

  // ---- qsk ----
  const int bq = blockIdx.x - 64;
  const int q0 = (bq >> 2) * 64;
  const int n0 = (bq & 3) * 64;
  const int ty = tid >> 4, tx = tid & 15;

  double acc[4][4];
#pragma unroll
  for (int i = 0; i < 4; ++i)
#pragma unroll
    for (int j = 0; j < 4; ++j) acc[i][j] = 0.0;

  const int arow = tid >> 2, aks = (tid & 3) * 8;
  const int qa = min(q0 + arow, NQ - 1);
  const int bkk = tid >> 3, bns = (tid & 7) * 8;

  for (int kc = 0; kc < 1024; kc += 32) {
    f32x4 av0 = *(const f32x4*)(emb + (size_t)qa * 1024 + kc + aks);
    f32x4 av1 = *(const f32x4*)(emb + (size_t)qa * 1024 + kc + aks + 4);
    f32x4 bv0 = *(const f32x4*)(adapter_w + (size_t)(kc + bkk) * 256 + n0 + bns);
    f32x4 bv1 = *(const f32x4*)(adapter_w + (size_t)(kc + bkk) * 256 + n0 + bns + 4);
    __syncthreads();
#pragma unroll
    for (int i = 0; i < 4; ++i) { As[arow][aks + i] = av0[i]; As[arow][aks + 4 + i] = av1[i]; }
#pragma unroll
    for (int i = 0; i < 4; ++i) { Bs[bkk][bns + i] = bv0[i]; Bs[bkk][bns + 4 + i] = bv1[i]; }
    __syncthreads();
#pragma unroll 4
    for (int kk = 0; kk < 32; ++kk) {
      double a[4], b[4];
#pragma unroll
      for (int i = 0; i < 4; ++i) a[i] = (double)As[ty * 4 + i][kk];
#pragma unroll
      for (int j = 0; j < 4; ++j) b[j] = (double)Bs[kk][tx * 4 + j];
#pragma unroll
      for (int i = 0; i < 4; ++i)
#pragma unroll
        for (int j = 0; j < 4; ++j) acc[i][j] = fma(a[i], b[j], acc[i][j]);
    }
  }
#pragma unroll
  for (int i = 0; i < 4; ++i) {
    const int qrow = q0 + ty * 4 + i;
    if (qrow < NQ) {
#pragma unroll
      for (int j = 0; j < 4; ++j) {
        const int n = n0 + tx * 4 + j;
        double v = acc[i][j] + (double)adapter_b[n];
        g_qs[(size_t)qrow * 256 + n] = v > 0.0 ? v : 0.0;
      }
    }
  }
}

// ---------------------------------------------------------------------------
// smallk: per q -> gru_in_q(64), r-folded xg table (fp32), lq(4).
// One block per q (R12 form; weights stream from L2).
// ---------------------------------------------------------------------------
__global__ void __launch_bounds__(256) smallk_kernel(
    const float* __restrict__ reducer_w, const float* __restrict__ gru_w_ih,
    const float* __restrict__ wgate_w)
{
  __shared__ double qsr[256];
  __shared__ double ps[4][64];
  __shared__ double gi[64];
  const int tid = threadIdx.x;
  const int qq = blockIdx.x;
  qsr[tid] = g_qs[(size_t)qq * 256 + tid];
  __syncthreads();
  {
    const int j = tid & 63, h = tid >> 6;
    const int k0 = h * 64;
    double a0 = 0.0, a1 = 0.0, a2 = 0.0, a3 = 0.0;
    for (int k = 0; k < 64; k += 4) {
      a0 = fma(qsr[k0 + k + 0], (double)reducer_w[(k0 + k + 0) * 64 + j], a0);
      a1 = fma(qsr[k0 + k + 1], (double)reducer_w[(k0 + k + 1) * 64 + j], a1);
      a2 = fma(qsr[k0 + k + 2], (double)reducer_w[(k0 + k + 2) * 64 + j], a2);
      a3 = fma(qsr[k0 + k + 3], (double)reducer_w[(k0 + k + 3) * 64 + j], a3);
    }
    ps[h][j] = (a0 + a1) + (a2 + a3);
  }
  __syncthreads();
  if (tid < 64) gi[tid] = (ps[0][tid] + ps[1][tid]) + (ps[2][tid] + ps[3][tid]);
  if (tid >= 64 && tid < 68) {
    const int e = tid - 64;
    double a0 = 0.0, a1 = 0.0, a2 = 0.0, a3 = 0.0;
    for (int k = 0; k < 256; k += 4) {
      a0 = fma(qsr[k + 0], (double)wgate_w[(k + 0) * 4 + e], a0);
      a1 = fma(qsr[k + 1], (double)wgate_w[(k + 1) * 4 + e], a1);
      a2 = fma(qsr[k + 2], (double)wgate_w[(k + 2) * 4 + e], a2);
      a3 = fma(qsr[k + 3], (double)wgate_w[(k + 3) * 4 + e], a3);
    }
    g_lq[(size_t)qq * 4 + e] = (a0 + a1) + (a2 + a3);
  }
  __syncthreads();
  if (tid < 192) {
    double a0 = 0.0, a1 = 0.0, a2 = 0.0, a3 = 0.0;
    for (int k = 0; k < 64; k += 4) {
      a0 = fma(gi[k + 0], (double)gru_w_ih[tid * 64 + k + 0], a0);
      a1 = fma(gi[k + 1], (double)gru_w_ih[tid * 64 + k + 1], a1);
      a2 = fma(gi[k + 2], (double)gru_w_ih[tid * 64 + k + 2], a2);
      a3 = fma(gi[k + 3], (double)gru_w_ih[tid * 64 + k + 3], a3);
    }
    const double s = (a0 + a1) + (a2 + a3);
    // r-folded x values (fp32): one extra rounding ~1e-8, below the
    // reference's own fp32 noise -> argmax decisions unaffected.
    g_xq2[(size_t)qq * 384 + tid]       = (float)(s + g_xgr[tid]);
    g_xq2[(size_t)qq * 384 + 192 + tid] = (float)(s + g_xgr[192 + tid]);
  }
}

// ---------------------------------------------------------------------------
// gruE: blocks 0..63 = gru (2-wave k-split, resident W, padded HF);
// blocks 64..1315 = kernelE (expert-split, flattened (313,4)).
// ---------------------------------------------------------------------------
__global__ void __attribute__((amdgpu_waves_per_eu(1, 1)))
__launch_bounds__(128, 1) gruE_kernel(
    const int* __restrict__ q, const int* __restrict__ r,
    const float* __restrict__ whh, const float* __restrict__ bhh,
    const float* __restrict__ emb,
    const float* __restrict__ b1, const float* __restrict__ b2,
    const float* __restrict__ lng, const float* __restrict__ lnb)
{
  __shared__ __align__(16) float HF[2][68];   // gru: h mirror, padded
  __shared__ __align__(16) unsigned short QR[32 * 264];
  __shared__ __align__(16) unsigned short H1[32 * 264];
  __shared__ __align__(16) unsigned short EO[32 * 264];
  const int tid = threadIdx.x;

  if (blockIdx.x < 64) {
    // ---- gru ----
    const int b = blockIdx.x;
    const int wv = tid >> 6;           // wave: rows [wv*32, wv*32+32)
    const int l = tid & 63;
    const int p = l >> 1;              // row within wave
    const int half = l & 1;            // k-half
    const int j = wv * 32 + p;         // row
    const int k0 = half * 32;

    // W half-rows for this lane, fp32 float2 pairs, resident (96 VGPRs).
    float2 Wr[16], Wz[16], Wn[16];
#pragma unroll
    for (int i = 0; i < 16; ++i) {
      Wr[i] = *(const float2*)(whh + (size_t)(0 * 64 + j) * 64 + k0 + 2 * i);
      Wz[i] = *(const float2*)(whh + (size_t)(1 * 64 + j) * 64 + k0 + 2 * i);
      Wn[i] = *(const float2*)(whh + (size_t)(2 * 64 + j) * 64 + k0 + 2 * i);
    }
#pragma unroll
    for (int i = 0; i < 16; ++i) {
      asm volatile("" : "+v"(Wr[i]));
      asm volatile("" : "+v"(Wz[i]));
      asm volatile("" : "+v"(Wn[i]));
    }
    const double br = (double)bhh[j];
    const double bz = (double)bhh[64 + j];
    const double bn = (double)bhh[128 + j];

    // step 0 consumes the start token (b_ih already folded in g_xg0f)
    float cx0 = g_xg0f[j], cx1 = g_xg0f[64 + j], cx2 = g_xg0f[128 + j];
    int qA = q[b * 512], rA = r[b * 512];

    const int jpad = j + ((j >> 5) << 2);     // +4 words for rows 32..63
    if (tid < 64) {
      const int tp = tid + ((tid >> 5) << 2);
      HF[0][tp] = 0.f;
    }
    double hd = 0.0;
    asm volatile("s_waitcnt lgkmcnt(0)\n\ts_barrier" ::: "memory");

    for (int t = 0; t < 512; ++t) {
      // prefetch x for step t+1 (token t) and q/r for token t+1
      float nx0 = 0.f, nx1 = 0.f, nx2 = 0.f;
      int qB = qA, rB = rA;
      if (t < 511) {
        const size_t base = (size_t)(qA * 2 + rA) * 192 + j;
        nx0 = g_xq2[base];
        nx1 = g_xq2[base + 64];
        nx2 = g_xq2[base + 128];
        const int tk = min(t + 1, 510);
        qB = q[b * 512 + tk];
        rB = r[b * 512 + tk];
      }

      // half-dot: 48 packed fp32 FMAs against resident W
      float2 ar = {0.f, 0.f}, az = {0.f, 0.f}, an = {0.f, 0.f};
      {
        const float4* hp = (const float4*)&HF[t & 1][half * 36];
#pragma unroll
        for (int g = 0; g < 8; ++g) {
          const float4 t4 = hp[g];
          const float2 hA = make_float2(t4.x, t4.y);
          const float2 hB = make_float2(t4.z, t4.w);
          pkfma(ar, Wr[2 * g], hA); pkfma(ar, Wr[2 * g + 1], hB);
          pkfma(az, Wz[2 * g], hA); pkfma(az, Wz[2 * g + 1], hB);
          pkfma(an, Wn[2 * g], hA); pkfma(an, Wn[2 * g + 1], hB);
        }
      }
      // combine k-halves in-pair (fp64 add is commutative -> pair-uniform)
      const float srh = ar.x + ar.y;
      const float szh = az.x + az.y;
      const float snh = an.x + an.y;
      const float sro = __shfl_xor(srh, 1);
      const float szo = __shfl_xor(szh, 1);
      const float sno = __shfl_xor(snh, 1);
      const double hr = br + ((double)srh + (double)sro);
      const double hz = bz + ((double)szh + (double)szo);
      const double hn = bn + ((double)snh + (double)sno);
      const double pr = (double)cx0 + hr, pz = (double)cx1 + hz;
      const double xn = (double)cx2;
      double rg = fma(0.5, tpoly(0.5 * pr), 0.5);
      double zg = fma(0.5, tpoly(0.5 * pz), 0.5);
      double pre = fma(rg, hn, xn);
      double ng = tpoly(pre);
      const bool bad = (fabs(pr) > 0.5) | (fabs(pz) > 0.5) | (fabs(pre) > 0.25);
      if (bad) {   // rare slow path
        rg = 1.0 / (1.0 + fexp(-pr));
        zg = 1.0 / (1.0 + fexp(-pz));
        pre = fma(rg, hn, xn);
        ng = 1.0 - 2.0 / (fexp(pre + pre) + 1.0);
      }
      const double hnew = fma(zg, hd - ng, ng);   // (1-z)n + z h
      hd = hnew;
      const float hnf = (float)hnew;
      if (half == 0) {
        HF[(t & 1) ^ 1][jpad] = hnf;
        g_m[((size_t)b * 512 + t) * 64 + j] = hnf;
      }
      asm volatile("s_waitcnt lgkmcnt(0)\n\ts_barrier" ::: "memory");

      cx0 = nx0; cx1 = nx1; cx2 = nx2;
      qA = qB; rA = rB;
    }
    return;
  }

  // ---- kernelE ----
  const int bx = blockIdx.x - 64;
  const int e  = bx & 3;
  const int t0 = (bx >> 2) * 32;
  const int w = tid >> 6;
  const int lane = tid & 63;
  const int l15 = lane & 15;
  const int quad = lane >> 4;

  // stage expert-e slice: 32 rows x 256 cols fp32 -> bf16
  for (int c = 0; c < 16; ++c) {
    const int idx = c * 128 + tid;           // f32x4 chunks: 32 rows x 64
    const int row = idx >> 6, col4 = idx & 63;
    const int qv = min(t0 + row, NQ - 1);
    f32x4 v = *(const f32x4*)(emb + (size_t)qv * 1024 + e * 256 + col4 * 4);
    unsigned a = ((unsigned)f2bf(v[1]) << 16) | f2bf(v[0]);
    unsigned bb = ((unsigned)f2bf(v[3]) << 16) | f2bf(v[2]);
    *(uint2*)&QR[row * 264 + col4 * 4] = make_uint2(a, bb);
  }
  __syncthreads();

  const f32x4 z4 = {0.f, 0.f, 0.f, 0.f};
  const int n0 = w * 128;

  f32x4 acc[2][8];
#pragma unroll
  for (int a = 0; a < 2; ++a)
#pragma unroll
    for (int bq = 0; bq < 8; ++bq) acc[a][bq] = z4;
#pragma unroll
  for (int ks = 0; ks < 8; ++ks) {
    const int koff = ks * 32 + quad * 8;
    bf16x8 a0 = *(const bf16x8*)&QR[l15 * 264 + koff];
    bf16x8 a1 = *(const bf16x8*)&QR[(16 + l15) * 264 + koff];
#pragma unroll
    for (int nt = 0; nt < 8; ++nt) {
      bf16x8 bbv = *(const bf16x8*)(g_w1t + (size_t)e * 65536 +
                                    (size_t)(n0 + nt * 16 + l15) * 256 + koff);
      acc[0][nt] = mfma16(a0, bbv, acc[0][nt]);
      acc[1][nt] = mfma16(a1, bbv, acc[1][nt]);
    }
  }
#pragma unroll
  for (int nt = 0; nt < 8; ++nt) {
    const int n = n0 + nt * 16 + l15;
    const float b1v = b1[e * 256 + n];
#pragma unroll
    for (int mt = 0; mt < 2; ++mt)
#pragma unroll
      for (int rg = 0; rg < 4; ++rg) {
        const int m = mt * 16 + quad * 4 + rg;
        H1[m * 264 + n] = f2bf(fmaxf(acc[mt][nt][rg] + b1v, 0.f));
      }
  }
  __syncthreads();

  f32x4 acc2[2][8];
#pragma unroll
  for (int a = 0; a < 2; ++a)
#pragma unroll
    for (int bq = 0; bq < 8; ++bq) acc2[a][bq] = z4;
#pragma unroll
  for (int ks = 0; ks < 8; ++ks) {
    const int koff = ks * 32 + quad * 8;
    bf16x8 a0 = *(const bf16x8*)&H1[l15 * 264 + koff];
    bf16x8 a1 = *(const bf16x8*)&H1[(16 + l15) * 264 + koff];
#pragma unroll
    for (int nt = 0; nt < 8; ++nt) {
      bf16x8 bbv = *(const bf16x8*)(g_w2t + (size_t)e * 65536 +
                                    (size_t)(n0 + nt * 16 + l15) * 256 + koff);
      acc2[0][nt] = mfma16(a0, bbv, acc2[0][nt]);
      acc2[1][nt] = mfma16(a1, bbv, acc2[1][nt]);
    }
  }
#pragma unroll
  for (int nt = 0; nt < 8; ++nt) {
    const int n = n0 + nt * 16 + l15;
    const float b2v = b2[e * 256 + n];
#pragma unroll
    for (int mt = 0; mt < 2; ++mt)
#pragma unroll
      for (int rg = 0; rg < 4; ++rg) {
        const int m = mt * 16 + quad * 4 + rg;
        EO[m * 264 + n] = f2bf(acc2[mt][nt][rg] + b2v);
      }
  }
  __syncthreads();

  {
    const int m = tid >> 2;
    const int sub = tid & 3;
    float sx = 0.f, sxx = 0.f;
#pragma unroll
    for (int i = 0; i < 8; ++i) {
      bf16x8 v = *(const bf16x8*)&EO[m * 264 + sub * 64 + i * 8];
#pragma unroll
      for (int c = 0; c < 8; ++c) {
        const float f = bf2f((unsigned short)v[c]);
        sx += f; sxx += f * f;
      }
    }
    sx += __shfl_xor(sx, 1); sxx += __shfl_xor(sxx, 1);
    sx += __shfl_xor(sx, 2); sxx += __shfl_xor(sxx, 2);
    const float mu = sx * (1.f / 256.f);
    const float var = sxx * (1.f / 256.f) - mu * mu;
    const float inv = 1.f / sqrtf(var + 1e-5f);
    if (t0 + m < NQ) {
      const size_t base = ((size_t)(t0 + m) * 4 + e) * 256;
#pragma unroll
      for (int i = 0; i < 8; ++i) {
        const int dbase = sub * 64 + i * 8;
        bf16x8 v = *(const bf16x8*)&EO[m * 264 + dbase];
        bf16x8 ov;
#pragma unroll
        for (int c = 0; c < 8; ++c) {
          const int d = dbase + c;
          const float f = bf2f((unsigned short)v[c]);
          ov[c] = (short)f2bf(lng[d] * (f - mu) * inv + lnb[d]);
        }
        *(bf16x8*)(g_qf + base + dbase) = ov;
      }
    }
  }
}

// ---------------------------------------------------------------------------
// kernelF: top1 fused.  Per 32 tokens: 4 lanes/token compute the exact
// per-e fp64 logit chains (same order as the old top1), 2-step strict->
// butterfly == sequential first-max; then gather qf[q_t][top1] -> q_fused
// out (fp32) and LDS; proj (cor|inc) bf16 MFMA; qa_fused by r.
// ---------------------------------------------------------------------------
__global__ void __launch_bounds__(128) kernelF(
    const int* __restrict__ q, const int* __restrict__ r,
    const float* __restrict__ wgate_w, const float* __restrict__ wgate_b,
    const float* __restrict__ pcb, const float* __restrict__ pib,
    float* __restrict__ out)
{
  __shared__ __align__(16) unsigned short QF[32 * 264];
  __shared__ double w2d[256];   // [j][e]
  __shared__ int rv_l[32];
  const int tid = threadIdx.x;
  const int t0 = blockIdx.x * 32;
  const int w = tid >> 6;
  const int lane = tid & 63;
  const int l15 = lane & 15;
  const int quad = lane >> 4;
  if (tid < 32) rv_l[tid] = r[t0 + tid];
  w2d[tid] = (double)wgate_w[1024 + tid];
  w2d[128 + tid] = (double)wgate_w[1152 + tid];
  __syncthreads();

  // ---- top1 (fused): token = tid>>2, e = tid&3 ----
  int bi;
  {
    const int tok = tid >> 2;
    const int e = tid & 3;
    const int t = t0 + tok;
    const int qv = q[t];
    double le = g_lq[(size_t)qv * 4 + e] + (double)wgate_b[e];
    const f32x4* mr4 = (const f32x4*)(g_m + (size_t)t * 64);
#pragma unroll 4
    for (int jj = 0; jj < 16; ++jj) {
      const f32x4 mv4 = mr4[jj];
#pragma unroll
      for (int c = 0; c < 4; ++c)
        le = fma((double)mv4[c], w2d[(jj * 4 + c) * 4 + e], le);
    }
    double v = le; bi = e;
    {   // pair {e,e^1}: winner = hi iff l_hi > l_lo (first-max)
      const double vo = __shfl_xor(v, 1);
      const int bo = __shfl_xor(bi, 1);
      const bool ilow = (e & 1) == 0;
      const double vl = ilow ? v : vo, vh = ilow ? vo : v;
      const int bl = ilow ? bi : bo, bh = ilow ? bo : bi;
      if (vh > vl) { v = vh; bi = bh; } else { v = vl; bi = bl; }
    }
    {   // pair {01,23}
      const double vo = __shfl_xor(v, 2);
      const int bo = __shfl_xor(bi, 2);
      const bool ilow = (e & 2) == 0;
      const double vl = ilow ? v : vo, vh = ilow ? vo : v;
      const int bl = ilow ? bi : bo, bh = ilow ? bo : bi;
      if (vh > vl) { v = vh; bi = bh; } else { v = vl; bi = bl; }
    }
  }

  {
    const int m = tid >> 2;
    const size_t row = ((size_t)q[t0 + m] * 4 + bi) * 256;
#pragma unroll
    for (int i = 0; i < 8; ++i) {
      const int dbase = (tid & 3) * 64 + i * 8;
      bf16x8 v = *(const bf16x8*)(g_qf + row + dbase);
      *(bf16x8*)&QF[m * 264 + dbase] = v;
      f32x4 f0, f1;
#pragma unroll
      for (int c = 0; c < 4; ++c) f0[c] = bf2f((unsigned short)v[c]);
#pragma unroll
      for (int c = 0; c < 4; ++c) f1[c] = bf2f((unsigned short)v[4 + c]);
      *(f32x4*)(out + (size_t)(t0 + m) * 256 + dbase) = f0;
      *(f32x4*)(out + (size_t)(t0 + m) * 256 + dbase + 4) = f1;
    }
  }
  __syncthreads();

  const f32x4 z4 = {0.f, 0.f, 0.f, 0.f};
  const int n0 = w * 128;
  for (int ph = 0; ph < 2; ++ph) {
    f32x4 acc[2][8];
#pragma unroll
    for (int a = 0; a < 2; ++a)
#pragma unroll
      for (int bq = 0; bq < 8; ++bq) acc[a][bq] = z4;
#pragma unroll
    for (int ks = 0; ks < 8; ++ks) {
      const int koff = ks * 32 + quad * 8;
      bf16x8 a0 = *(const bf16x8*)&QF[l15 * 264 + koff];
      bf16x8 a1 = *(const bf16x8*)&QF[(16 + l15) * 264 + koff];
#pragma unroll
      for (int nt = 0; nt < 8; ++nt) {
        bf16x8 bbv = *(const bf16x8*)(g_projt +
            (size_t)(ph * 256 + n0 + nt * 16 + l15) * 256 + koff);
        acc[0][nt] = mfma16(a0, bbv, acc[0][nt]);
        acc[1][nt] = mfma16(a1, bbv, acc[1][nt]);
      }
    }
    const float* pbb = ph ? pib : pcb;
    const int want = ph ? 0 : 1;
#pragma unroll
    for (int nt = 0; nt < 8; ++nt) {
      const int n = n0 + nt * 16 + l15;
      const float pbv = pbb[n];
#pragma unroll
      for (int mt = 0; mt < 2; ++mt)
#pragma unroll
        for (int rg = 0; rg < 4; ++rg) {
          const int m = mt * 16 + quad * 4 + rg;
          if (rv_l[m] == want)
            out[(size_t)TT * 256 + (size_t)(t0 + m) * 256 + n] =
                acc[mt][nt][rg] + pbv;
        }
    }
  }
}

// ---------------------------------------------------------------------------
extern "C" void kernel_launch(void* const* d_in, const int* in_sizes, int n_in,
                              void* d_out, int out_size, void* d_ws, size_t ws_size,
                              hipStream_t stream)
{
  const int*   q   = (const int*)d_in[0];
  const int*   r   = (const int*)d_in[1];
  const float* emb = (const float*)d_in[2];
  const float* ew1 = (const float*)d_in[3];
  const float* eb1 = (const float*)d_in[4];
  const float* ew2 = (const float*)d_in[5];
  const float* eb2 = (const float*)d_in[6];
  const float* aw  = (const float*)d_in[7];
  const float* ab  = (const float*)d_in[8];
  const float* rw  = (const float*)d_in[9];
  const float* rb  = (const float*)d_in[10];
  const float* st  = (const float*)d_in[11];
  const float* wih = (const float*)d_in[12];
  const float* whh = (const float*)d_in[13];
  const float* bih = (const float*)d_in[14];
  const float* bhh = (const float*)d_in[15];
  const float* wgw = (const float*)d_in[16];
  const float* wgb = (const float*)d_in[17];
  const float* lng = (const float*)d_in[18];
  const float* lnb = (const float*)d_in[19];
  const float* resp= (const float*)d_in[20];
  const float* pcw = (const float*)d_in[21];
  const float* pcb = (const float*)d_in[22];
  const float* piw = (const float*)d_in[23];
  const float* pib = (const float*)d_in[24];
  float* out = (float*)d_out;
  (void)bih; (void)in_sizes; (void)n_in; (void)d_ws; (void)ws_size; (void)out_size;

  prepqsk_kernel<<<692, 256, 0, stream>>>(ew1, ew2, pcw, piw, resp, rw, rb, st,
                                          wih, bih, emb, aw, ab);
  smallk_kernel<<<NQ, 256, 0, stream>>>(rw, wih, wgw);
  gruE_kernel<<<64 + 313 * 4, 128, 0, stream>>>(q, r, whh, bhh,
                                                emb, eb1, eb2, lng, lnb);
  kernelF<<<1024, 128, 0, stream>>>(q, r, wgw, wgb, pcb, pib, out);
}